// Round 7
// baseline (334.480 us; speedup 1.0000x reference)
//
#include <hip/hip_runtime.h>
#include <hip/hip_bf16.h>
#include <math.h>

#define NB 2        // batch
#define NC 64       // channels
#define ND 8        // head dim (C/8)
#define NN 4096     // tokens (T*W*H)
#define NM 256      // landmarks
#define NL 16       // N/M
#define SCALE 0.35355339059327373f  // 1/sqrt(8)
// real root of z^3 - 7z^2 + 15z - 13 and cofactors: (z-A)(z^2+Bz+C)
#define A_ROOT 4.1303956f
#define B_COEF (-2.8696044f)
#define C_COEF 3.1474086f

typedef __attribute__((ext_vector_type(4))) float f32x4;
typedef __attribute__((ext_vector_type(8))) short bf16x8;

__device__ inline ushort f2bf(float f) {
  __hip_bfloat16 h = __float2bfloat16(f);
  return *reinterpret_cast<ushort*>(&h);
}
__device__ inline float bf2f(ushort u) {
  return __uint_as_float(((unsigned int)u) << 16);
}

// async global->LDS, 16B per lane; LDS dest must be wave-linear (base + lane*16)
__device__ inline void gl_lds16(const void* g, void* l) {
  __builtin_amdgcn_global_load_lds(
      (const __attribute__((address_space(1))) unsigned int*)g,
      (__attribute__((address_space(3))) unsigned int*)l, 16, 0, 0);
}

// ---------------- qkv projection + fused landmark means ----------------
__global__ __launch_bounds__(256) void qkv2l_kernel(
    const float* __restrict__ x,
    const float* __restrict__ wq, const float* __restrict__ bq,
    const float* __restrict__ wk, const float* __restrict__ bk,
    const float* __restrict__ wv, const float* __restrict__ bv,
    float* __restrict__ q, float* __restrict__ k, float* __restrict__ v,
    float* __restrict__ ql, float* __restrict__ kl) {
  __shared__ float ws[NC];
  int o = blockIdx.x;            // 0..79: 0-7 q, 8-15 k, 16-79 v
  int b = blockIdx.z;
  int n0 = blockIdx.y * 1024;
  int t = threadIdx.x;
  const float* wrow;
  float bias;
  if (o < ND)            { wrow = wq + (size_t)o * NC;            bias = bq[o]; }
  else if (o < 2 * ND)   { wrow = wk + (size_t)(o - ND) * NC;     bias = bk[o - ND]; }
  else                   { wrow = wv + (size_t)(o - 2 * ND) * NC; bias = bv[o - 2 * ND]; }
  if (t < NC) ws[t] = wrow[t];
  __syncthreads();
  int n = n0 + t * 4;
  float4 acc = {bias, bias, bias, bias};
  #pragma unroll
  for (int c = 0; c < NC; ++c) {
    float wc = ws[c];
    float4 xv = *(const float4*)(x + ((size_t)b * NC + c) * NN + n);
    acc.x += wc * xv.x; acc.y += wc * xv.y; acc.z += wc * xv.z; acc.w += wc * xv.w;
  }
  if (o < ND) {
    float* qp = q + ((size_t)b * NN + n) * ND + o;
    qp[0] = acc.x; qp[8] = acc.y; qp[16] = acc.z; qp[24] = acc.w;
  } else if (o < 2 * ND) {
    float* kp = k + ((size_t)b * NN + n) * ND + (o - ND);
    kp[0] = acc.x; kp[8] = acc.y; kp[16] = acc.z; kp[24] = acc.w;
  } else {
    *(float4*)(v + ((size_t)b * NC + (o - 2 * ND)) * NN + n) = acc;
  }
  // fused landmark: group of 16 tokens = 4 consecutive threads (wave-aligned quads)
  if (o < 2 * ND) {
    float s4 = acc.x + acc.y + acc.z + acc.w;
    s4 += __shfl_xor(s4, 1);
    s4 += __shfl_xor(s4, 2);
    if ((t & 3) == 0) {
      int g = n0 / 16 + (t >> 2);
      float* dst = (o < ND) ? ql : kl;
      dst[((size_t)b * NM + g) * ND + (o & 7)] = s4 * (1.0f / 16.0f);
    }
  }
}

// ---------------- merged softmaxes (k1 bf16, k2 f32, k3 f32) + kv zero ----------------
__global__ __launch_bounds__(256) void scores_all_kernel(
    const float* __restrict__ q, const float* __restrict__ ql,
    const float* __restrict__ kw, const float* __restrict__ kl,
    ushort* __restrict__ k1bf, float* __restrict__ k2w,
    float* __restrict__ k3w, float* __restrict__ kvw) {
  __shared__ float skl[NM][9];
  __shared__ float wred[4], wsum[4];
  int blk = blockIdx.x;
  int t = threadIdx.x;
  if (blk < 2048 + 128) {
    const float* Q; int R, b, xrow;
    bool isbf;
    if (blk < 2048) { b = blk >> 10; xrow = blk & 1023; Q = q;  R = NN; isbf = true; }
    else { int r = blk - 2048; b = r >> 6; xrow = r & 63; Q = ql; R = NM; isbf = false; }
    for (int i = t; i < NM * ND; i += 256) skl[i >> 3][i & 7] = kl[(size_t)b * NM * ND + i];
    __syncthreads();
    int wave = t >> 6, lane = t & 63;
    int r = xrow * 4 + wave;
    const float* qrow = Q + ((size_t)b * R + r) * ND;
    float qr[ND];
    #pragma unroll
    for (int dd = 0; dd < ND; ++dd) qr[dd] = qrow[dd];
    float sc[4];
    float lmax = -1e30f;
    #pragma unroll
    for (int s = 0; s < 4; ++s) {
      int j = lane + 64 * s;
      float a = 0.f;
      #pragma unroll
      for (int dd = 0; dd < ND; ++dd) a += qr[dd] * skl[j][dd];
      sc[s] = a * SCALE;
      lmax = fmaxf(lmax, sc[s]);
    }
    for (int off = 32; off; off >>= 1) lmax = fmaxf(lmax, __shfl_xor(lmax, off));
    float lsum = 0.f;
    #pragma unroll
    for (int s = 0; s < 4; ++s) { sc[s] = expf(sc[s] - lmax); lsum += sc[s]; }
    for (int off = 32; off; off >>= 1) lsum += __shfl_xor(lsum, off);
    float inv = 1.0f / lsum;
    if (isbf) {
      #pragma unroll
      for (int s = 0; s < 4; ++s)
        k1bf[((size_t)b * R + r) * NM + lane + 64 * s] = f2bf(sc[s] * inv);
    } else {
      #pragma unroll
      for (int s = 0; s < 4; ++s)
        k2w[((size_t)b * R + r) * NM + lane + 64 * s] = sc[s] * inv;
    }
  } else if (blk < 2048 + 128 + 512) {
    int r = blk - 2176;
    int b = r >> 8, i = r & 255;
    float qr[ND];
    #pragma unroll
    for (int dd = 0; dd < ND; ++dd) qr[dd] = ql[((size_t)b * NM + i) * ND + dd];
    float sc[16];
    float lmax = -1e30f;
    #pragma unroll
    for (int s = 0; s < 16; ++s) {
      int n = t + 256 * s;
      const float* kp = kw + ((size_t)b * NN + n) * ND;
      float a = 0.f;
      #pragma unroll
      for (int dd = 0; dd < ND; ++dd) a += qr[dd] * kp[dd];
      sc[s] = a * SCALE;
      lmax = fmaxf(lmax, sc[s]);
    }
    for (int off = 32; off; off >>= 1) lmax = fmaxf(lmax, __shfl_xor(lmax, off));
    if ((t & 63) == 0) wred[t >> 6] = lmax;
    __syncthreads();
    lmax = fmaxf(fmaxf(wred[0], wred[1]), fmaxf(wred[2], wred[3]));
    float lsum = 0.f;
    #pragma unroll
    for (int s = 0; s < 16; ++s) { sc[s] = expf(sc[s] - lmax); lsum += sc[s]; }
    for (int off = 32; off; off >>= 1) lsum += __shfl_xor(lsum, off);
    if ((t & 63) == 0) wsum[t >> 6] = lsum;
    __syncthreads();
    lsum = wsum[0] + wsum[1] + wsum[2] + wsum[3];
    float inv = 1.0f / lsum;
    #pragma unroll
    for (int s = 0; s < 16; ++s) k3w[((size_t)b * NM + i) * NN + t + 256 * s] = sc[s] * inv;
  } else {
    int r = blk - 2688;
    kvw[r * 256 + t] = 0.0f;
  }
}

// ---------------- denom + k3 -> k3T bf16 transpose + split-K kv ----------------
__global__ __launch_bounds__(256) void denom_k3t_kv_kernel(
    const float* __restrict__ k2, float* __restrict__ denw,
    const float* __restrict__ k3, ushort* __restrict__ k3t,
    const float* __restrict__ vw, float* __restrict__ kvw) {
  __shared__ char smem[34048];
  int blk = blockIdx.x;
  int t = threadIdx.x;
  if (blk < NB) {
    float* red = (float*)smem;
    int b = blk;
    float cs = 0.f;
    for (int i = 0; i < NM; ++i) cs += k2[((size_t)b * NM + i) * NM + t];
    red[t] = cs;
    __syncthreads();
    for (int off = 128; off; off >>= 1) {
      if (t < off) red[t] = fmaxf(red[t], red[t + off]);
      __syncthreads();
    }
    if (t == 0) denw[b] = red[0];
  } else if (blk < NB + 2048) {
    typedef float TRow[33];
    TRow* tile = (TRow*)smem;
    int r = blk - NB;
    int n0 = (r & 127) * 32, m0 = ((r >> 7) & 7) * 32, b = r >> 10;
    int rr = t >> 3, c4 = (t & 7) * 4;
    float4 v = *(const float4*)(k3 + ((size_t)b * NM + m0 + rr) * NN + n0 + c4);
    tile[c4][rr] = v.x; tile[c4 + 1][rr] = v.y; tile[c4 + 2][rr] = v.z; tile[c4 + 3][rr] = v.w;
    __syncthreads();
    ushort4 u;
    u.x = f2bf(tile[rr][c4]);     u.y = f2bf(tile[rr][c4 + 1]);
    u.z = f2bf(tile[rr][c4 + 2]); u.w = f2bf(tile[rr][c4 + 3]);
    *(ushort4*)(k3t + ((size_t)b * NN + n0 + rr) * NM + m0 + c4) = u;
  } else {
    // kv split-K: kv[b][p][c] = sum_j k3[b][p][j] * v[b][c][j]
    typedef float KVRow[33];
    KVRow* Ks = (KVRow*)smem;
    KVRow* Vs = (KVRow*)(smem + 64 * 33 * 4);
    int r = blk - (NB + 2048);
    int bp = (r & 3) * 64;
    int jsl = (r >> 2) & 31;
    int b = r >> 7;
    int j0base = jsl * (NN / 32);
    int tx = t & 15, ty = t >> 4;
    int lrow = t >> 2, ljc = (t & 3) * 8;
    float acc[4][4] = {};
    for (int j0 = j0base; j0 < j0base + NN / 32; j0 += 32) {
      float4 a0 = *(const float4*)(k3 + ((size_t)b * NM + bp + lrow) * NN + j0 + ljc);
      float4 a1 = *(const float4*)(k3 + ((size_t)b * NM + bp + lrow) * NN + j0 + ljc + 4);
      float4 v0 = *(const float4*)(vw + ((size_t)b * NC + lrow) * NN + j0 + ljc);
      float4 v1 = *(const float4*)(vw + ((size_t)b * NC + lrow) * NN + j0 + ljc + 4);
      Ks[lrow][ljc + 0] = a0.x; Ks[lrow][ljc + 1] = a0.y; Ks[lrow][ljc + 2] = a0.z; Ks[lrow][ljc + 3] = a0.w;
      Ks[lrow][ljc + 4] = a1.x; Ks[lrow][ljc + 5] = a1.y; Ks[lrow][ljc + 6] = a1.z; Ks[lrow][ljc + 7] = a1.w;
      Vs[lrow][ljc + 0] = v0.x; Vs[lrow][ljc + 1] = v0.y; Vs[lrow][ljc + 2] = v0.z; Vs[lrow][ljc + 3] = v0.w;
      Vs[lrow][ljc + 4] = v1.x; Vs[lrow][ljc + 5] = v1.y; Vs[lrow][ljc + 6] = v1.z; Vs[lrow][ljc + 7] = v1.w;
      __syncthreads();
      #pragma unroll
      for (int kk = 0; kk < 32; ++kk) {
        float av_[4], bv_[4];
        #pragma unroll
        for (int i = 0; i < 4; ++i) av_[i] = Ks[(ty << 2) + i][kk];
        #pragma unroll
        for (int j = 0; j < 4; ++j) bv_[j] = Vs[(tx << 2) + j][kk];
        #pragma unroll
        for (int i = 0; i < 4; ++i)
          #pragma unroll
          for (int j = 0; j < 4; ++j) acc[i][j] += av_[i] * bv_[j];
      }
      __syncthreads();
    }
    #pragma unroll
    for (int i = 0; i < 4; ++i)
      #pragma unroll
      for (int j = 0; j < 4; ++j)
        atomicAdd(&kvw[((size_t)b * NM + bp + (ty << 2) + i) * NC + (tx << 2) + j], acc[i][j]);
  }
}

// ---------------- NS tile core: 32x32 tile, full K=256, single barrier ----------------
// amode: 0 = A plain; 2 = A_eff = A^T * dval  (used for virtual V0 = k2^T*dval)
// bmode: 0 = B plain; 2 = B_eff = B^T * dval; 3 = B_eff = B + B_COEF*Bp + C_COEF*I
// wmode: 0 = write fp32 O; 1 = write bf16 transposed Ot
__device__ __forceinline__ void ns_core(
    const float* __restrict__ A, int amode,
    const float* __restrict__ B, int bmode, const float* __restrict__ Bp,
    float dval, float s_a, float s_ab,
    float* __restrict__ O, ushort* __restrict__ Ot, int wmode,
    int bi, int bj, size_t bo, float (*As)[260], float (*Bs)[36], int t) {
  if (amode == 0) {
    #pragma unroll
    for (int q = 0; q < 8; ++q) {
      int s = q * 256 + t;
      int r = s >> 6, kc = (s & 63) * 4;
      *(float4*)&As[r][kc] = *(const float4*)(A + bo + (size_t)(bi + r) * NM + kc);
    }
  } else {
    #pragma unroll
    for (int q = 0; q < 8; ++q) {
      int s = q * 256 + t;
      int k = s >> 3, rc = (s & 7) * 4;
      float4 v = *(const float4*)(A + bo + (size_t)k * NM + bi + rc);
      As[rc + 0][k] = v.x * dval; As[rc + 1][k] = v.y * dval;
      As[rc + 2][k] = v.z * dval; As[rc + 3][k] = v.w * dval;
    }
  }
  if (bmode == 0) {
    #pragma unroll
    for (int q = 0; q < 8; ++q) {
      int s = q * 256 + t;
      int k = s >> 3, c = (s & 7) * 4;
      *(float4*)&Bs[k][c] = *(const float4*)(B + bo + (size_t)k * NM + bj + c);
    }
  } else if (bmode == 2) {
    #pragma unroll
    for (int q = 0; q < 8; ++q) {
      int s = q * 256 + t;
      int c = s >> 6, k4 = (s & 63) * 4;
      float4 v = *(const float4*)(B + bo + (size_t)(bj + c) * NM + k4);
      Bs[k4 + 0][c] = v.x * dval; Bs[k4 + 1][c] = v.y * dval;
      Bs[k4 + 2][c] = v.z * dval; Bs[k4 + 3][c] = v.w * dval;
    }
  } else {
    #pragma unroll
    for (int q = 0; q < 8; ++q) {
      int s = q * 256 + t;
      int k = s >> 3, c = (s & 7) * 4;
      float4 v = *(const float4*)(B + bo + (size_t)k * NM + bj + c);
      float4 z = *(const float4*)(Bp + bo + (size_t)k * NM + bj + c);
      float4 rr;
      rr.x = v.x + B_COEF * z.x; rr.y = v.y + B_COEF * z.y;
      rr.z = v.z + B_COEF * z.z; rr.w = v.w + B_COEF * z.w;
      int d = k - bj - c;
      if (d >= 0 && d < 4) ((float*)&rr)[d] += C_COEF;
      *(float4*)&Bs[k][c] = rr;
    }
  }
  __syncthreads();
  int tx = t & 15, ty = t >> 4;
  float acc[2][2] = {};
  #pragma unroll 8
  for (int kk = 0; kk < NM; ++kk) {
    float a0 = As[ty * 2][kk], a1 = As[ty * 2 + 1][kk];
    float b0 = Bs[kk][tx * 2], b1 = Bs[kk][tx * 2 + 1];
    acc[0][0] += a0 * b0; acc[0][1] += a0 * b1;
    acc[1][0] += a1 * b0; acc[1][1] += a1 * b1;
  }
  #pragma unroll
  for (int i = 0; i < 2; ++i)
    #pragma unroll
    for (int j = 0; j < 2; ++j) {
      int R = bi + ty * 2 + i, C = bj + tx * 2 + j;
      float rv = s_ab * acc[i][j];
      if (s_a != 0.0f) {
        float av;
        if (amode == 2) av = A[bo + (size_t)C * NM + R] * dval;
        else            av = A[bo + (size_t)R * NM + C];
        rv += s_a * av;
      }
      if (wmode == 0) O[bo + (size_t)R * NM + C] = rv;
      else            Ot[bo + (size_t)C * NM + R] = f2bf(rv);
    }
}

// Z = k2 @ V  (bmode 2: V virtual = k2^T * dval)
__global__ __launch_bounds__(256) void ns_z_kernel(
    const float* __restrict__ k2, const float* __restrict__ V, int bmode,
    const float* __restrict__ denw, float* __restrict__ Z) {
  __shared__ float As[32][260];
  __shared__ float Bs[256][36];
  int bj = blockIdx.x * 32, bi = blockIdx.y * 32, b = blockIdx.z;
  size_t bo = (size_t)b * NM * NM;
  float dval = (bmode == 2) ? 1.0f / fmaxf(denw[0], denw[1]) : 0.f;
  ns_core(k2, 0, (bmode == 2) ? k2 : V, bmode, nullptr, dval, 0.f, 1.f,
          Z, nullptr, 0, bi, bj, bo, As, Bs, threadIdx.x);
}

// dual launch: z<NB -> U = V@Z - a*V ; z>=NB -> Z2 = Z@Z
__global__ __launch_bounds__(256) void ns_uz2_kernel(
    const float* __restrict__ Vc, int amode, const float* __restrict__ Z,
    const float* __restrict__ denw, float* __restrict__ U, float* __restrict__ Z2) {
  __shared__ float As[32][260];
  __shared__ float Bs[256][36];
  int bj = blockIdx.x * 32, bi = blockIdx.y * 32, z = blockIdx.z;
  if (z < NB) {
    size_t bo = (size_t)z * NM * NM;
    float dval = (amode == 2) ? 1.0f / fmaxf(denw[0], denw[1]) : 0.f;
    ns_core(Vc, amode, Z, 0, nullptr, dval, -A_ROOT, 1.f,
            U, nullptr, 0, bi, bj, bo, As, Bs, threadIdx.x);
  } else {
    size_t bo = (size_t)(z - NB) * NM * NM;
    ns_core(Z, 0, Z, 0, nullptr, 0.f, 0.f, 1.f,
            Z2, nullptr, 0, bi, bj, bo, As, Bs, threadIdx.x);
  }
}

// V' = -0.25 * U @ (Z2 + B_COEF*Z + C_COEF*I); wmode1 -> write bf16 transposed Vinvt
__global__ __launch_bounds__(256) void ns_v_kernel(
    const float* __restrict__ U, const float* __restrict__ Z2,
    const float* __restrict__ Z, float* __restrict__ Vout,
    ushort* __restrict__ Vinvt, int wmode) {
  __shared__ float As[32][260];
  __shared__ float Bs[256][36];
  int bj = blockIdx.x * 32, bi = blockIdx.y * 32, b = blockIdx.z;
  size_t bo = (size_t)b * NM * NM;
  ns_core(U, 0, Z2, 3, Z, 0.f, 0.f, -0.25f,
          Vout, Vinvt, wmode, bi, bj, bo, As, Bs, threadIdx.x);
}

// ---------------- A = k1 @ Vinv via bf16 MFMA (global_load_lds staging) ----------------
__global__ __launch_bounds__(256) void gemm_a_mfma(
    const ushort* __restrict__ k1bf, const ushort* __restrict__ Vt,
    ushort* __restrict__ Abf) {
  int b = blockIdx.z;
  int bi = blockIdx.y * 128, bj = blockIdx.x * 128;
  __shared__ ushort As[128 * 64];
  __shared__ ushort Bs[128 * 64];
  int t = threadIdx.x;
  int wave = t >> 6, lane = t & 63;
  int wr = wave >> 1, wc = wave & 1;
  const ushort* Ab = k1bf + (size_t)b * NN * NM;
  const ushort* Bb = Vt + (size_t)b * NM * NM;
  f32x4 acc[4][4] = {};
  for (int k0 = 0; k0 < NM; k0 += 64) {
    #pragma unroll
    for (int q = 0; q < 4; ++q) {
      int s = q * 256 + t;
      int r = s >> 3, c = s & 7;
      int cs = (c ^ (r & 7)) << 3;
      gl_lds16(Ab + (size_t)(bi + r) * NM + k0 + cs, As + (size_t)s * 8);
      gl_lds16(Bb + (size_t)(bj + r) * NM + k0 + cs, Bs + (size_t)s * 8);
    }
    __syncthreads();
    #pragma unroll
    for (int kk = 0; kk < 2; ++kk) {
      int koff = kk * 64 + (lane >> 4) * 16;
      bf16x8 af[4], bfv[4];
      #pragma unroll
      for (int mi = 0; mi < 4; ++mi) {
        int row = wr * 64 + mi * 16 + (lane & 15);
        af[mi] = *(const bf16x8*)((const char*)As + row * 128 + (koff ^ ((row & 7) << 4)));
      }
      #pragma unroll
      for (int nj = 0; nj < 4; ++nj) {
        int row = wc * 64 + nj * 16 + (lane & 15);
        bfv[nj] = *(const bf16x8*)((const char*)Bs + row * 128 + (koff ^ ((row & 7) << 4)));
      }
      #pragma unroll
      for (int mi = 0; mi < 4; ++mi)
        #pragma unroll
        for (int nj = 0; nj < 4; ++nj)
          acc[mi][nj] = __builtin_amdgcn_mfma_f32_16x16x32_bf16(af[mi], bfv[nj], acc[mi][nj], 0, 0, 0);
    }
    __syncthreads();
  }
  int col = lane & 15, rbase = (lane >> 4) * 4;
  #pragma unroll
  for (int mi = 0; mi < 4; ++mi)
    #pragma unroll
    for (int nj = 0; nj < 4; ++nj)
      #pragma unroll
      for (int r = 0; r < 4; ++r)
        Abf[((size_t)b * NN + bi + wr * 64 + mi * 16 + rbase + r) * NM
            + bj + wc * 64 + nj * 16 + col] = f2bf(acc[mi][nj][r]);
}

// ---------------- merged: attn = A @ k3 (bf16 MFMA, XCD swizzle) + out ----------------
__global__ __launch_bounds__(256) void attn_out_kernel(
    const ushort* __restrict__ Abf, const ushort* __restrict__ K3T,
    float* __restrict__ attn, const float* __restrict__ kvm,
    const float* __restrict__ x, const float* __restrict__ gamma,
    float* __restrict__ outp) {
  __shared__ char smem[32768];
  int blk = blockIdx.x;
  int t = threadIdx.x;
  if (blk < 2048) {
    ushort* As = (ushort*)smem;
    ushort* Bs = (ushort*)(smem + 16384);
    int swz = (blk & 7) * 256 + (blk >> 3);   // bijective XCD swizzle (2048 % 8 == 0)
    int b = swz >> 10;
    int rem = swz & 1023;
    int bi = (rem >> 5) * 128, bj = (rem & 31) * 128;
    int wave = t >> 6, lane = t & 63;
    int wr = wave >> 1, wc = wave & 1;
    const ushort* Ab = Abf + (size_t)b * NN * NM;
    const ushort* Bb = K3T + (size_t)b * NN * NM;
    f32x4 acc[4][4] = {};
    for (int k0 = 0; k0 < NM; k0 += 64) {
      #pragma unroll
      for (int q = 0; q < 4; ++q) {
        int s = q * 256 + t;
        int r = s >> 3, c = s & 7;
        int cs = (c ^ (r & 7)) << 3;
        gl_lds16(Ab + (size_t)(bi + r) * NM + k0 + cs, As + (size_t)s * 8);
        gl_lds16(Bb + (size_t)(bj + r) * NM + k0 + cs, Bs + (size_t)s * 8);
      }
      __syncthreads();
      #pragma unroll
      for (int kk = 0; kk < 2; ++kk) {
        int koff = kk * 64 + (lane >> 4) * 16;
        bf16x8 af[4], bfv[4];
        #pragma unroll
        for (int mi = 0; mi < 4; ++mi) {
          int row = wr * 64 + mi * 16 + (lane & 15);
          af[mi] = *(const bf16x8*)((const char*)As + row * 128 + (koff ^ ((row & 7) << 4)));
        }
        #pragma unroll
        for (int nj = 0; nj < 4; ++nj) {
          int row = wc * 64 + nj * 16 + (lane & 15);
          bfv[nj] = *(const bf16x8*)((const char*)Bs + row * 128 + (koff ^ ((row & 7) << 4)));
        }
        #pragma unroll
        for (int mi = 0; mi < 4; ++mi)
          #pragma unroll
          for (int nj = 0; nj < 4; ++nj)
            acc[mi][nj] = __builtin_amdgcn_mfma_f32_16x16x32_bf16(af[mi], bfv[nj], acc[mi][nj], 0, 0, 0);
      }
      __syncthreads();
    }
    int col = lane & 15, rbase = (lane >> 4) * 4;
    #pragma unroll
    for (int mi = 0; mi < 4; ++mi)
      #pragma unroll
      for (int nj = 0; nj < 4; ++nj)
        #pragma unroll
        for (int r = 0; r < 4; ++r)
          attn[((size_t)b * NN + bi + wr * 64 + mi * 16 + rbase + r) * NN
               + bj + wc * 64 + nj * 16 + col] = acc[mi][nj][r];
  } else {
    // out = gamma*(A@kv) + x
    float* Asf = (float*)smem;
    int r = blk - 2048;
    int b = r >> 7, n0 = (r & 127) * 32;
    for (int it = 0; it < 32; ++it)
      Asf[it * 256 + (t ^ (it & 31))] = bf2f(Abf[((size_t)b * NN + n0 + it) * NM + t]);
    __syncthreads();
    int tn = t & 31, cg0 = (t >> 5) * 8;
    float g = gamma[0];
    float acc[8] = {};
    for (int p = 0; p < NM; ++p) {
      float a = Asf[tn * 256 + (p ^ (tn & 31))];
      float4 kv0 = *(const float4*)(kvm + ((size_t)b * NM + p) * NC + cg0);
      float4 kv1 = *(const float4*)(kvm + ((size_t)b * NM + p) * NC + cg0 + 4);
      acc[0] += a * kv0.x; acc[1] += a * kv0.y; acc[2] += a * kv0.z; acc[3] += a * kv0.w;
      acc[4] += a * kv1.x; acc[5] += a * kv1.y; acc[6] += a * kv1.z; acc[7] += a * kv1.w;
    }
    #pragma unroll
    for (int qd = 0; qd < 8; ++qd) {
      int c = cg0 + qd;
      size_t idx = ((size_t)b * NC + c) * NN + n0 + tn;
      outp[idx] = g * acc[qd] + x[idx];
    }
  }
}

extern "C" void kernel_launch(void* const* d_in, const int* in_sizes, int n_in,
                              void* d_out, int out_size, void* d_ws, size_t ws_size,
                              hipStream_t stream) {
  const float* x     = (const float*)d_in[0];
  const float* wq    = (const float*)d_in[1];
  const float* bq    = (const float*)d_in[2];
  const float* wk    = (const float*)d_in[3];
  const float* bk    = (const float*)d_in[4];
  const float* wv    = (const float*)d_in[5];
  const float* bv    = (const float*)d_in[6];
  const float* gamma = (const float*)d_in[7];
  float* outp = (float*)d_out;                       // [B][C][N]
  float* attn = outp + (size_t)NB * NC * NN;         // [B][N][N]
  float* w = (float*)d_ws;

  float* qw   = w;                 // [B][N][D]    65536
  float* kw   = qw + 65536;        // [B][N][D]    65536
  float* vw   = kw + 65536;        // [B][C][N]    524288
  float* qlw  = vw + 524288;       // [B][M][D]    4096
  float* klw  = qlw + 4096;        // [B][M][D]    4096
  float* k1w  = klw + 4096;        // 8 MB region: k1bf (4MB) + k3T (4MB)
  float* k2w  = k1w + 2097152;     // [B][M][M]    131072
  float* k3w  = k2w + 131072;      // [B][M][N]    2097152
  float* Abuf = k3w + 2097152;     // 4 MB region: Abf bf16
  float* Zb   = Abuf + 1048576;    // [B][M][M]    131072
  float* Z2b  = Zb + 131072;       // [B][M][M]    131072
  float* Ub   = Z2b + 131072;      // [B][M][M]    131072
  float* Vab  = Ub + 131072;       // [B][M][M]    131072
  float* Vtw  = Vab + 131072;      // Vinvt bf16   65536 floats
  float* kvw  = Vtw + 65536;       // [B][M][C]    32768
  float* denw = kvw + 32768;       // [2]
  ushort* k1bf  = (ushort*)k1w;                 // [B][N][M] bf16
  ushort* k3T   = (ushort*)k1w + 2097152;       // [B][N][M] bf16 (k3^T)
  ushort* Abf   = (ushort*)Abuf;                // [B][N][M] bf16
  ushort* Vinvt = (ushort*)Vtw;                 // [B][M][M] bf16 (Vinv^T)

  qkv2l_kernel<<<dim3(80, NN / 1024, NB), dim3(256), 0, stream>>>(
      x, wq, bq, wk, bk, wv, bv, qw, kw, vw, qlw, klw);
  scores_all_kernel<<<dim3(2048 + 128 + 512 + 128), dim3(256), 0, stream>>>(
      qw, qlw, kw, klw, k1bf, k2w, k3w, kvw);
  denom_k3t_kv_kernel<<<dim3(NB + 2048 + 256), dim3(256), 0, stream>>>(
      k2w, denw, k3w, k3T, vw, kvw);

  // Newton-Schulz via factored cubic: 3 launches per iteration, 18 total.
  for (int it = 0; it < 6; ++it) {
    int vm = (it == 0) ? 2 : 0;
    ns_z_kernel<<<dim3(8, 8, NB), dim3(256), 0, stream>>>(k2w, Vab, vm, denw, Zb);
    ns_uz2_kernel<<<dim3(8, 8, 2 * NB), dim3(256), 0, stream>>>(
        (it == 0) ? k2w : Vab, vm, Zb, denw, Ub, Z2b);
    ns_v_kernel<<<dim3(8, 8, NB), dim3(256), 0, stream>>>(
        Ub, Z2b, Zb, Vab, Vinvt, (it == 5) ? 1 : 0);
  }

  gemm_a_mfma<<<dim3(NM / 128, NN / 128, NB), dim3(256), 0, stream>>>(k1bf, Vinvt, Abf);
  attn_out_kernel<<<dim3(2048 + 256), dim3(256), 0, stream>>>(
      Abf, k3T, attn, kvw, x, gamma, outp);
}

// Round 8
// 312.355 us; speedup vs baseline: 1.0708x; 1.0708x over previous
//
#include <hip/hip_runtime.h>
#include <hip/hip_bf16.h>
#include <math.h>

#define NB 2        // batch
#define NC 64       // channels
#define ND 8        // head dim (C/8)
#define NN 4096     // tokens (T*W*H)
#define NM 256      // landmarks
#define NL 16       // N/M
#define SCALE 0.35355339059327373f  // 1/sqrt(8)
// p(z) = 13-15z+7z^2-z^3 = (A_ROOT - z)(z^2 + B_COEF z + C_COEF)
#define A_ROOT 4.1303956f
#define B_COEF (-2.8696044f)
#define C_COEF 3.1474086f

typedef __attribute__((ext_vector_type(4))) float f32x4;
typedef __attribute__((ext_vector_type(8))) short bf16x8;

__device__ inline ushort f2bf(float f) {
  __hip_bfloat16 h = __float2bfloat16(f);
  return *reinterpret_cast<ushort*>(&h);
}
__device__ inline float bf2f(ushort u) {
  return __uint_as_float(((unsigned int)u) << 16);
}

// async global->LDS, 16B per lane; LDS dest must be wave-linear (base + lane*16)
__device__ inline void gl_lds16(const void* g, void* l) {
  __builtin_amdgcn_global_load_lds(
      (const __attribute__((address_space(1))) unsigned int*)g,
      (__attribute__((address_space(3))) unsigned int*)l, 16, 0, 0);
}

// ---------------- qkv projection, output-row parallel (R5) ----------------
__global__ __launch_bounds__(256) void qkv2_kernel(
    const float* __restrict__ x,
    const float* __restrict__ wq, const float* __restrict__ bq,
    const float* __restrict__ wk, const float* __restrict__ bk,
    const float* __restrict__ wv, const float* __restrict__ bv,
    float* __restrict__ q, float* __restrict__ k, float* __restrict__ v) {
  __shared__ float ws[NC];
  int o = blockIdx.x;            // 0..79: 0-7 q, 8-15 k, 16-79 v
  int b = blockIdx.z;
  int n0 = blockIdx.y * 1024;
  int t = threadIdx.x;
  const float* wrow;
  float bias;
  if (o < ND)            { wrow = wq + (size_t)o * NC;            bias = bq[o]; }
  else if (o < 2 * ND)   { wrow = wk + (size_t)(o - ND) * NC;     bias = bk[o - ND]; }
  else                   { wrow = wv + (size_t)(o - 2 * ND) * NC; bias = bv[o - 2 * ND]; }
  if (t < NC) ws[t] = wrow[t];
  __syncthreads();
  int n = n0 + t * 4;
  float4 acc = {bias, bias, bias, bias};
  #pragma unroll
  for (int c = 0; c < NC; ++c) {
    float wc = ws[c];
    float4 xv = *(const float4*)(x + ((size_t)b * NC + c) * NN + n);
    acc.x += wc * xv.x; acc.y += wc * xv.y; acc.z += wc * xv.z; acc.w += wc * xv.w;
  }
  if (o < ND) {
    float* qp = q + ((size_t)b * NN + n) * ND + o;
    qp[0] = acc.x; qp[8] = acc.y; qp[16] = acc.z; qp[24] = acc.w;
  } else if (o < 2 * ND) {
    float* kp = k + ((size_t)b * NN + n) * ND + (o - ND);
    kp[0] = acc.x; kp[8] = acc.y; kp[16] = acc.z; kp[24] = acc.w;
  } else {
    *(float4*)(v + ((size_t)b * NC + (o - 2 * ND)) * NN + n) = acc;
  }
}

// ---------------- landmarks (R5) ----------------
__global__ void landmark_kernel(const float* __restrict__ q, const float* __restrict__ k,
                                float* __restrict__ ql, float* __restrict__ kl) {
  int idx = blockIdx.x * 256 + threadIdx.x;
  int b = idx / (NM * ND), r = idx % (NM * ND), i = r / ND, o = r % ND;
  float sq = 0.f, sk = 0.f;
  for (int l = 0; l < NL; ++l) {
    size_t base = ((size_t)b * NN + i * NL + l) * ND + o;
    sq += q[base]; sk += k[base];
  }
  ql[idx] = sq * (1.0f / NL);
  kl[idx] = sk * (1.0f / NL);
}

// ---------------- softmax rows vs landmarks: bf16 output (k1) ----------------
__global__ __launch_bounds__(256) void scores_softmax_m_bf16(
    const float* __restrict__ Q, int R, const float* __restrict__ KL,
    ushort* __restrict__ out) {
  __shared__ float skl[NM][9];
  int b = blockIdx.y;
  int t = threadIdx.x;
  for (int i = t; i < NM * ND; i += 256) skl[i >> 3][i & 7] = KL[(size_t)b * NM * ND + i];
  __syncthreads();
  int wave = t >> 6, lane = t & 63;
  int r = blockIdx.x * 4 + wave;
  const float* qrow = Q + ((size_t)b * R + r) * ND;
  float qr[ND];
  #pragma unroll
  for (int dd = 0; dd < ND; ++dd) qr[dd] = qrow[dd];
  float sc[4];
  float lmax = -1e30f;
  #pragma unroll
  for (int s = 0; s < 4; ++s) {
    int j = lane + 64 * s;
    float a = 0.f;
    #pragma unroll
    for (int dd = 0; dd < ND; ++dd) a += qr[dd] * skl[j][dd];
    sc[s] = a * SCALE;
    lmax = fmaxf(lmax, sc[s]);
  }
  for (int off = 32; off; off >>= 1) lmax = fmaxf(lmax, __shfl_xor(lmax, off));
  float lsum = 0.f;
  #pragma unroll
  for (int s = 0; s < 4; ++s) { sc[s] = expf(sc[s] - lmax); lsum += sc[s]; }
  for (int off = 32; off; off >>= 1) lsum += __shfl_xor(lsum, off);
  float inv = 1.0f / lsum;
  #pragma unroll
  for (int s = 0; s < 4; ++s)
    out[((size_t)b * R + r) * NM + lane + 64 * s] = f2bf(sc[s] * inv);
}

// ---------------- softmax rows vs landmarks: fp32 output (k2) ----------------
__global__ __launch_bounds__(256) void scores_softmax_m_f32(
    const float* __restrict__ Q, int R, const float* __restrict__ KL,
    float* __restrict__ out) {
  __shared__ float skl[NM][9];
  int b = blockIdx.y;
  int t = threadIdx.x;
  for (int i = t; i < NM * ND; i += 256) skl[i >> 3][i & 7] = KL[(size_t)b * NM * ND + i];
  __syncthreads();
  int wave = t >> 6, lane = t & 63;
  int r = blockIdx.x * 4 + wave;
  const float* qrow = Q + ((size_t)b * R + r) * ND;
  float qr[ND];
  #pragma unroll
  for (int dd = 0; dd < ND; ++dd) qr[dd] = qrow[dd];
  float sc[4];
  float lmax = -1e30f;
  #pragma unroll
  for (int s = 0; s < 4; ++s) {
    int j = lane + 64 * s;
    float a = 0.f;
    #pragma unroll
    for (int dd = 0; dd < ND; ++dd) a += qr[dd] * skl[j][dd];
    sc[s] = a * SCALE;
    lmax = fmaxf(lmax, sc[s]);
  }
  for (int off = 32; off; off >>= 1) lmax = fmaxf(lmax, __shfl_xor(lmax, off));
  float lsum = 0.f;
  #pragma unroll
  for (int s = 0; s < 4; ++s) { sc[s] = expf(sc[s] - lmax); lsum += sc[s]; }
  for (int off = 32; off; off >>= 1) lsum += __shfl_xor(lsum, off);
  float inv = 1.0f / lsum;
  #pragma unroll
  for (int s = 0; s < 4; ++s) out[((size_t)b * R + r) * NM + lane + 64 * s] = sc[s] * inv;
}

// ---------------- k3 softmax (fp32 out) ----------------
__global__ __launch_bounds__(256) void scores_softmax_n(
    const float* __restrict__ QL, const float* __restrict__ Kt,
    float* __restrict__ out) {
  __shared__ float wred[4], wsum[4];
  int b = blockIdx.y, i = blockIdx.x;
  int t = threadIdx.x;
  float qr[ND];
  #pragma unroll
  for (int dd = 0; dd < ND; ++dd) qr[dd] = QL[((size_t)b * NM + i) * ND + dd];
  float sc[16];
  float lmax = -1e30f;
  #pragma unroll
  for (int s = 0; s < 16; ++s) {
    int n = t + 256 * s;
    const float* kp = Kt + ((size_t)b * NN + n) * ND;
    float a = 0.f;
    #pragma unroll
    for (int dd = 0; dd < ND; ++dd) a += qr[dd] * kp[dd];
    sc[s] = a * SCALE;
    lmax = fmaxf(lmax, sc[s]);
  }
  for (int off = 32; off; off >>= 1) lmax = fmaxf(lmax, __shfl_xor(lmax, off));
  if ((t & 63) == 0) wred[t >> 6] = lmax;
  __syncthreads();
  lmax = fmaxf(fmaxf(wred[0], wred[1]), fmaxf(wred[2], wred[3]));
  float lsum = 0.f;
  #pragma unroll
  for (int s = 0; s < 16; ++s) { sc[s] = expf(sc[s] - lmax); lsum += sc[s]; }
  for (int off = 32; off; off >>= 1) lsum += __shfl_xor(lsum, off);
  if ((t & 63) == 0) wsum[t >> 6] = lsum;
  __syncthreads();
  lsum = wsum[0] + wsum[1] + wsum[2] + wsum[3];
  float inv = 1.0f / lsum;
  #pragma unroll
  for (int s = 0; s < 16; ++s) out[((size_t)b * NM + i) * NN + t + 256 * s] = sc[s] * inv;
}

// ---------------- denom: max column-sum per batch ----------------
__global__ __launch_bounds__(256) void denom_kernel(const float* __restrict__ k2,
                                                    float* __restrict__ denw) {
  __shared__ float red[256];
  int b = blockIdx.x;
  int t = threadIdx.x;
  float cs = 0.f;
  for (int i = 0; i < NM; ++i) cs += k2[((size_t)b * NM + i) * NM + t];
  red[t] = cs;
  __syncthreads();
  for (int off = 128; off; off >>= 1) {
    if (t < off) red[t] = fmaxf(red[t], red[t + off]);
    __syncthreads();
  }
  if (t == 0) denw[b] = red[0];
}

// ---------------- V0 = k2^T * invdenom ----------------
__global__ void vinit_kernel(const float* __restrict__ k2, const float* __restrict__ denw,
                             float* __restrict__ V) {
  int idx = blockIdx.x * 256 + threadIdx.x;
  int b = idx / (NM * NM), r = idx % (NM * NM), i = r / NM, j = r % NM;
  float dval = 1.0f / fmaxf(denw[0], denw[1]);
  V[idx] = k2[((size_t)b * NM + j) * NM + i] * dval;
}

// ================= NS chain: R5-staging tile core + independent padding ==========
#define NS_SMEM 70144   // As 32x260x4 (33280) + Bs 256x36x4 (36864)

// padding work: p < 2048 -> cvt_t tile (k3 fp32 -> k3T bf16); else kv split-K slice
__device__ __forceinline__ void pad_work(
    int p, const float* __restrict__ k3, ushort* __restrict__ k3t,
    const float* __restrict__ vw, float* __restrict__ kvw, char* smem, int t) {
  if (p < 2048) {
    typedef float TRow[33];
    TRow* tile = (TRow*)smem;
    int n0 = (p & 127) * 32, m0 = ((p >> 7) & 7) * 32, b = p >> 10;
    int rr = t >> 3, c4 = (t & 7) * 4;
    float4 v = *(const float4*)(k3 + ((size_t)b * NM + m0 + rr) * NN + n0 + c4);
    tile[c4][rr] = v.x; tile[c4 + 1][rr] = v.y; tile[c4 + 2][rr] = v.z; tile[c4 + 3][rr] = v.w;
    __syncthreads();
    ushort4 u;
    u.x = f2bf(tile[rr][c4]);     u.y = f2bf(tile[rr][c4 + 1]);
    u.z = f2bf(tile[rr][c4 + 2]); u.w = f2bf(tile[rr][c4 + 3]);
    *(ushort4*)(k3t + ((size_t)b * NN + n0 + rr) * NM + m0 + c4) = u;
  } else {
    typedef float KVRow[33];
    KVRow* Ks = (KVRow*)smem;
    KVRow* Vs = (KVRow*)(smem + 64 * 33 * 4);
    int p2 = p - 2048;
    int bp = (p2 & 3) * 64;
    int jsl = (p2 >> 2) & 31;
    int b = p2 >> 7;
    int j0base = jsl * (NN / 32);
    int tx = t & 15, ty = t >> 4;
    int lrow = t >> 2, ljc = (t & 3) * 8;
    float acc[4][4] = {};
    for (int j0 = j0base; j0 < j0base + NN / 32; j0 += 32) {
      float4 a0 = *(const float4*)(k3 + ((size_t)b * NM + bp + lrow) * NN + j0 + ljc);
      float4 a1 = *(const float4*)(k3 + ((size_t)b * NM + bp + lrow) * NN + j0 + ljc + 4);
      float4 v0 = *(const float4*)(vw + ((size_t)b * NC + lrow) * NN + j0 + ljc);
      float4 v1 = *(const float4*)(vw + ((size_t)b * NC + lrow) * NN + j0 + ljc + 4);
      Ks[lrow][ljc + 0] = a0.x; Ks[lrow][ljc + 1] = a0.y; Ks[lrow][ljc + 2] = a0.z; Ks[lrow][ljc + 3] = a0.w;
      Ks[lrow][ljc + 4] = a1.x; Ks[lrow][ljc + 5] = a1.y; Ks[lrow][ljc + 6] = a1.z; Ks[lrow][ljc + 7] = a1.w;
      Vs[lrow][ljc + 0] = v0.x; Vs[lrow][ljc + 1] = v0.y; Vs[lrow][ljc + 2] = v0.z; Vs[lrow][ljc + 3] = v0.w;
      Vs[lrow][ljc + 4] = v1.x; Vs[lrow][ljc + 5] = v1.y; Vs[lrow][ljc + 6] = v1.z; Vs[lrow][ljc + 7] = v1.w;
      __syncthreads();
      #pragma unroll
      for (int kk = 0; kk < 32; ++kk) {
        float av_[4], bv_[4];
        #pragma unroll
        for (int i = 0; i < 4; ++i) av_[i] = Ks[(ty << 2) + i][kk];
        #pragma unroll
        for (int j = 0; j < 4; ++j) bv_[j] = Vs[(tx << 2) + j][kk];
        #pragma unroll
        for (int i = 0; i < 4; ++i)
          #pragma unroll
          for (int j = 0; j < 4; ++j) acc[i][j] += av_[i] * bv_[j];
      }
      __syncthreads();
    }
    #pragma unroll
    for (int i = 0; i < 4; ++i)
      #pragma unroll
      for (int j = 0; j < 4; ++j)
        atomicAdd(&kvw[((size_t)b * NM + bp + (ty << 2) + i) * NC + (tx << 2) + j], acc[i][j]);
  }
}

// 32x32 output tile, full K=256, single barrier (R5 gemm_rk32 structure).
// B2 == nullptr: B plain.  B2 != nullptr: B_eff = B + B_COEF*B2 + C_COEF*I.
// O = s_ab * (A @ B_eff) + s_a * A
__device__ __forceinline__ void ns_tile(
    const float* __restrict__ A, const float* __restrict__ B,
    const float* __restrict__ B2, float* __restrict__ O,
    float s_a, float s_ab, size_t bo, int bi, int bj, char* smem, int t) {
  typedef float ARow[260];
  typedef float BRow[36];
  ARow* As = (ARow*)smem;
  BRow* Bs = (BRow*)(smem + 33280);
  #pragma unroll
  for (int q = 0; q < 8; ++q) {
    int s = q * 256 + t;
    int ar = s >> 6, ac = (s & 63) * 4;
    *(float4*)&As[ar][ac] = *(const float4*)(A + bo + (size_t)(bi + ar) * NM + ac);
    int bk = s >> 3, bc = (s & 7) * 4;
    if (B2 == nullptr) {
      *(float4*)&Bs[bk][bc] = *(const float4*)(B + bo + (size_t)bk * NM + bj + bc);
    } else {
      float4 v = *(const float4*)(B + bo + (size_t)bk * NM + bj + bc);
      float4 z = *(const float4*)(B2 + bo + (size_t)bk * NM + bj + bc);
      float4 rr;
      rr.x = v.x + B_COEF * z.x; rr.y = v.y + B_COEF * z.y;
      rr.z = v.z + B_COEF * z.z; rr.w = v.w + B_COEF * z.w;
      int d = bk - bj - bc;
      if (d >= 0 && d < 4) ((float*)&rr)[d] += C_COEF;
      *(float4*)&Bs[bk][bc] = rr;
    }
  }
  __syncthreads();
  int tx = t & 15, ty = t >> 4;
  float acc[2][2] = {};
  #pragma unroll 8
  for (int kk = 0; kk < NM; ++kk) {
    float a0 = As[ty * 2][kk], a1 = As[ty * 2 + 1][kk];
    float b0 = Bs[kk][tx * 2], b1 = Bs[kk][tx * 2 + 1];
    acc[0][0] += a0 * b0; acc[0][1] += a0 * b1;
    acc[1][0] += a1 * b0; acc[1][1] += a1 * b1;
  }
  #pragma unroll
  for (int i = 0; i < 2; ++i)
    #pragma unroll
    for (int j = 0; j < 2; ++j) {
      size_t o = bo + (size_t)(bi + ty * 2 + i) * NM + bj + tx * 2 + j;
      float r = s_ab * acc[i][j];
      if (s_a != 0.0f) r += s_a * A[o];
      O[o] = r;
    }
}

// Z = k2 @ V    [+128 pad blocks]
__global__ __launch_bounds__(256) void ns_z_kernel(
    const float* __restrict__ k2, const float* __restrict__ V, float* __restrict__ Z,
    const float* __restrict__ k3, ushort* __restrict__ k3t,
    const float* __restrict__ vw, float* __restrict__ kvw, int padBase) {
  __shared__ char smem[NS_SMEM];
  int blk = blockIdx.x, t = threadIdx.x;
  if (blk < NB * 64) {
    int b = blk >> 6, tile = blk & 63;
    int bi = (tile >> 3) * 32, bj = (tile & 7) * 32;
    ns_tile(k2, V, nullptr, Z, 0.f, 1.f, (size_t)b * NM * NM, bi, bj, smem, t);
  } else {
    pad_work(padBase + blk - NB * 64, k3, k3t, vw, kvw, smem, t);
  }
}

// dual: blk<128 -> U = V@Z - a*V ; blk<256 -> Z2 = Z@Z   [+128 pad]
__global__ __launch_bounds__(256) void ns_uz2_kernel(
    const float* __restrict__ V, const float* __restrict__ Z,
    float* __restrict__ U, float* __restrict__ Z2,
    const float* __restrict__ k3, ushort* __restrict__ k3t,
    const float* __restrict__ vw, float* __restrict__ kvw, int padBase) {
  __shared__ char smem[NS_SMEM];
  int blk = blockIdx.x, t = threadIdx.x;
  if (blk < NB * 64) {
    int b = blk >> 6, tile = blk & 63;
    int bi = (tile >> 3) * 32, bj = (tile & 7) * 32;
    ns_tile(V, Z, nullptr, U, -A_ROOT, 1.f, (size_t)b * NM * NM, bi, bj, smem, t);
  } else if (blk < 2 * NB * 64) {
    int r = blk - NB * 64;
    int b = r >> 6, tile = r & 63;
    int bi = (tile >> 3) * 32, bj = (tile & 7) * 32;
    ns_tile(Z, Z, nullptr, Z2, 0.f, 1.f, (size_t)b * NM * NM, bi, bj, smem, t);
  } else {
    pad_work(padBase + blk - 2 * NB * 64, k3, k3t, vw, kvw, smem, t);
  }
}

// V' = -0.25 * U @ (Z2 + B_COEF*Z + C_COEF*I)   [+128 pad]
__global__ __launch_bounds__(256) void ns_v_kernel(
    const float* __restrict__ U, const float* __restrict__ Z2,
    const float* __restrict__ Z, float* __restrict__ Vout,
    const float* __restrict__ k3, ushort* __restrict__ k3t,
    const float* __restrict__ vw, float* __restrict__ kvw, int padBase) {
  __shared__ char smem[NS_SMEM];
  int blk = blockIdx.x, t = threadIdx.x;
  if (blk < NB * 64) {
    int b = blk >> 6, tile = blk & 63;
    int bi = (tile >> 3) * 32, bj = (tile & 7) * 32;
    ns_tile(U, Z2, Z, Vout, 0.f, -0.25f, (size_t)b * NM * NM, bi, bj, smem, t);
  } else {
    pad_work(padBase + blk - NB * 64, k3, k3t, vw, kvw, smem, t);
  }
}

// ---------------- Vinv fp32 -> bf16 transposed (R5) ----------------
__global__ __launch_bounds__(256) void cvt_vinv_kernel(const float* __restrict__ Va,
                                                       ushort* __restrict__ Vt) {
  int b = blockIdx.z;
  int n0 = blockIdx.x * 32, m0 = blockIdx.y * 32;
  __shared__ float tile[32][33];
  int t = threadIdx.x;
  int r = t >> 3, c4 = (t & 7) * 4;
  float4 v = *(const float4*)(Va + ((size_t)b * NM + m0 + r) * NM + n0 + c4);
  tile[c4][r] = v.x; tile[c4 + 1][r] = v.y; tile[c4 + 2][r] = v.z; tile[c4 + 3][r] = v.w;
  __syncthreads();
  ushort4 u;
  u.x = f2bf(tile[r][c4]);     u.y = f2bf(tile[r][c4 + 1]);
  u.z = f2bf(tile[r][c4 + 2]); u.w = f2bf(tile[r][c4 + 3]);
  *(ushort4*)(Vt + ((size_t)b * NM + n0 + r) * NM + m0 + c4) = u;
}

// ---------------- A = k1 @ Vinv via bf16 MFMA (R5) ----------------
__global__ __launch_bounds__(256) void gemm_a_mfma(
    const ushort* __restrict__ k1bf, const ushort* __restrict__ Vt,
    ushort* __restrict__ Abf) {
  int b = blockIdx.z;
  int bi = blockIdx.y * 128, bj = blockIdx.x * 128;
  __shared__ ushort As[128 * 64];
  __shared__ ushort Bs[128 * 64];
  int t = threadIdx.x;
  int wave = t >> 6, lane = t & 63;
  int wr = wave >> 1, wc = wave & 1;
  const ushort* Ab = k1bf + (size_t)b * NN * NM;
  const ushort* Bb = Vt + (size_t)b * NM * NM;
  f32x4 acc[4][4] = {};
  for (int k0 = 0; k0 < NM; k0 += 64) {
    #pragma unroll
    for (int q = 0; q < 4; ++q) {
      int s = q * 256 + t;
      int r = s >> 3, c = s & 7;
      int cs = (c ^ (r & 7)) << 3;
      gl_lds16(Ab + (size_t)(bi + r) * NM + k0 + cs, As + (size_t)s * 8);
      gl_lds16(Bb + (size_t)(bj + r) * NM + k0 + cs, Bs + (size_t)s * 8);
    }
    __syncthreads();
    #pragma unroll
    for (int kk = 0; kk < 2; ++kk) {
      int koff = kk * 64 + (lane >> 4) * 16;
      bf16x8 af[4], bfv[4];
      #pragma unroll
      for (int mi = 0; mi < 4; ++mi) {
        int row = wr * 64 + mi * 16 + (lane & 15);
        af[mi] = *(const bf16x8*)((const char*)As + row * 128 + (koff ^ ((row & 7) << 4)));
      }
      #pragma unroll
      for (int nj = 0; nj < 4; ++nj) {
        int row = wc * 64 + nj * 16 + (lane & 15);
        bfv[nj] = *(const bf16x8*)((const char*)Bs + row * 128 + (koff ^ ((row & 7) << 4)));
      }
      #pragma unroll
      for (int mi = 0; mi < 4; ++mi)
        #pragma unroll
        for (int nj = 0; nj < 4; ++nj)
          acc[mi][nj] = __builtin_amdgcn_mfma_f32_16x16x32_bf16(af[mi], bfv[nj], acc[mi][nj], 0, 0, 0);
    }
    __syncthreads();
  }
  int col = lane & 15, rbase = (lane >> 4) * 4;
  #pragma unroll
  for (int mi = 0; mi < 4; ++mi)
    #pragma unroll
    for (int nj = 0; nj < 4; ++nj)
      #pragma unroll
      for (int r = 0; r < 4; ++r)
        Abf[((size_t)b * NN + bi + wr * 64 + mi * 16 + rbase + r) * NM
            + bj + wc * 64 + nj * 16 + col] = f2bf(acc[mi][nj][r]);
}

// ---------------- attn = A @ k3 via bf16 MFMA, 128x128 tile, XCD swizzle (R5) ----------------
__global__ __launch_bounds__(256) void gemm_attn_mfma(
    const ushort* __restrict__ Abf, const ushort* __restrict__ K3T,
    float* __restrict__ attn) {
  int lin = blockIdx.z * 1024 + blockIdx.y * 32 + blockIdx.x;
  int swz = (lin & 7) * 256 + (lin >> 3);
  int b = swz >> 10;
  int rem = swz & 1023;
  int bi = (rem >> 5) * 128, bj = (rem & 31) * 128;
  __shared__ ushort As[128 * 64];
  __shared__ ushort Bs[128 * 64];
  int t = threadIdx.x;
  int wave = t >> 6, lane = t & 63;
  int wr = wave >> 1, wc = wave & 1;
  const ushort* Ab = Abf + (size_t)b * NN * NM;
  const ushort* Bb = K3T + (size_t)b * NN * NM;
  f32x4 acc[4][4] = {};
  for (int k0 = 0; k0 < NM; k0 += 64) {
    #pragma unroll
    for (int q = 0; q < 4; ++q) {
      int s = q * 256 + t;
      int r = s >> 3, c = s & 7;
      int cs = (c ^ (r & 7)) << 3;
      gl_lds16(Ab + (size_t)(bi + r) * NM + k0 + cs, As + (size_t)s * 8);
      gl_lds16(Bb + (size_t)(bj + r) * NM + k0 + cs, Bs + (size_t)s * 8);
    }
    __syncthreads();
    #pragma unroll
    for (int kk = 0; kk < 2; ++kk) {
      int koff = kk * 64 + (lane >> 4) * 16;
      bf16x8 af[4], bfv[4];
      #pragma unroll
      for (int mi = 0; mi < 4; ++mi) {
        int row = wr * 64 + mi * 16 + (lane & 15);
        af[mi] = *(const bf16x8*)((const char*)As + row * 128 + (koff ^ ((row & 7) << 4)));
      }
      #pragma unroll
      for (int nj = 0; nj < 4; ++nj) {
        int row = wc * 64 + nj * 16 + (lane & 15);
        bfv[nj] = *(const bf16x8*)((const char*)Bs + row * 128 + (koff ^ ((row & 7) << 4)));
      }
      #pragma unroll
      for (int mi = 0; mi < 4; ++mi)
        #pragma unroll
        for (int nj = 0; nj < 4; ++nj)
          acc[mi][nj] = __builtin_amdgcn_mfma_f32_16x16x32_bf16(af[mi], bfv[nj], acc[mi][nj], 0, 0, 0);
    }
    __syncthreads();
  }
  int col = lane & 15, rbase = (lane >> 4) * 4;
  #pragma unroll
  for (int mi = 0; mi < 4; ++mi)
    #pragma unroll
    for (int nj = 0; nj < 4; ++nj)
      #pragma unroll
      for (int r = 0; r < 4; ++r)
        attn[((size_t)b * NN + bi + wr * 64 + mi * 16 + rbase + r) * NN
             + bj + wc * 64 + nj * 16 + col] = acc[mi][nj][r];
  }

// ---------------- out = gamma*(A@kv) + x  (A in bf16, R5) ----------------
__global__ __launch_bounds__(256) void out_kernel(
    const ushort* __restrict__ Abf, const float* __restrict__ kvm,
    const float* __restrict__ x, const float* __restrict__ gamma,
    float* __restrict__ outp) {
  __shared__ float As[32 * 256];
  int blk = blockIdx.x;
  int b = blk / (NN / 32), n0 = (blk % (NN / 32)) * 32;
  int t = threadIdx.x;
  for (int it = 0; it < 32; ++it)
    As[it * 256 + (t ^ (it & 31))] = bf2f(Abf[((size_t)b * NN + n0 + it) * NM + t]);
  __syncthreads();
  int tn = t & 31, cg0 = (t >> 5) * 8;
  float g = gamma[0];
  float acc[8] = {};
  for (int p = 0; p < NM; ++p) {
    float a = As[tn * 256 + (p ^ (tn & 31))];
    float4 kv0 = *(const float4*)(kvm + ((size_t)b * NM + p) * NC + cg0);
    float4 kv1 = *(const float4*)(kvm + ((size_t)b * NM + p) * NC + cg0 + 4);
    acc[0] += a * kv0.x; acc[1] += a * kv0.y; acc[2] += a * kv0.z; acc[3] += a * kv0.w;
    acc[4] += a * kv1.x; acc[5] += a * kv1.y; acc[6] += a * kv1.z; acc[7] += a * kv1.w;
  }
  #pragma unroll
  for (int qd = 0; qd < 8; ++qd) {
    int c = cg0 + qd;
    size_t idx = ((size_t)b * NC + c) * NN + n0 + tn;
    outp[idx] = g * acc[qd] + x[idx];
  }
}

extern "C" void kernel_launch(void* const* d_in, const int* in_sizes, int n_in,
                              void* d_out, int out_size, void* d_ws, size_t ws_size,
                              hipStream_t stream) {
  const float* x     = (const float*)d_in[0];
  const float* wq    = (const float*)d_in[1];
  const float* bq    = (const float*)d_in[2];
  const float* wk    = (const float*)d_in[3];
  const float* bk    = (const float*)d_in[4];
  const float* wv    = (const float*)d_in[5];
  const float* bv    = (const float*)d_in[6];
  const float* gamma = (const float*)d_in[7];
  float* outp = (float*)d_out;                       // [B][C][N]
  float* attn = outp + (size_t)NB * NC * NN;         // [B][N][N]
  float* w = (float*)d_ws;

  float* qw   = w;                 // [B][N][D]    65536
  float* kw   = qw + 65536;        // [B][N][D]    65536
  float* vw   = kw + 65536;        // [B][C][N]    524288
  float* qlw  = vw + 524288;       // [B][M][D]    4096
  float* klw  = qlw + 4096;        // [B][M][D]    4096
  float* k1w  = klw + 4096;        // 8 MB region: k1bf (4MB) + k3T (4MB)
  float* k2w  = k1w + 2097152;     // [B][M][M]    131072
  float* k3w  = k2w + 131072;      // [B][M][N]    2097152
  float* Abuf = k3w + 2097152;     // 4 MB region: Abf bf16
  float* Zb   = Abuf + 1048576;    // [B][M][M]    131072
  float* Z2b  = Zb + 131072;       // [B][M][M]    131072
  float* Ub   = Z2b + 131072;      // [B][M][M]    131072
  float* Va   = Ub + 131072;       // [B][M][M]    131072
  float* Vtw  = Va + 131072;       // Vinvt bf16   65536 floats
  float* kvw  = Vtw + 65536;       // [B][M][C]    32768
  float* denw = kvw + 32768;       // [2]
  ushort* k1bf  = (ushort*)k1w;                 // [B][N][M] bf16
  ushort* k3T   = (ushort*)k1w + 2097152;       // [B][N][M] bf16 (k3^T)
  ushort* Abf   = (ushort*)Abuf;                // [B][N][M] bf16
  ushort* Vinvt = (ushort*)Vtw;                 // [B][M][M] bf16 (Vinv^T)

  hipMemsetAsync(kvw, 0, (size_t)NB * NM * NC * sizeof(float), stream);
  qkv2_kernel<<<dim3(80, NN / 1024, NB), dim3(256), 0, stream>>>(
      x, wq, bq, wk, bk, wv, bv, qw, kw, vw);
  landmark_kernel<<<dim3(NB * NM * ND / 256), dim3(256), 0, stream>>>(qw, kw, qlw, klw);
  scores_softmax_m_bf16<<<dim3(NN / 4, NB), dim3(256), 0, stream>>>(qw, NN, klw, k1bf);
  scores_softmax_m_f32<<<dim3(NM / 4, NB), dim3(256), 0, stream>>>(qlw, NM, klw, k2w);
  scores_softmax_n<<<dim3(NM, NB), dim3(256), 0, stream>>>(qlw, kw, k3w);
  denom_kernel<<<dim3(NB), dim3(256), 0, stream>>>(k2w, denw);
  vinit_kernel<<<dim3(NB * NM * NM / 256), dim3(256), 0, stream>>>(k2w, denw, Va);

  // Newton-Schulz: 6 iters x 3 launches; each launch carries 128 padding blocks
  // that execute the independent cvt_t (2048) + kv (256) work. 18*128 = 2304.
  int padBase = 0;
  for (int it = 0; it < 6; ++it) {
    ns_z_kernel<<<dim3(NB * 64 + 128), dim3(256), 0, stream>>>(
        k2w, Va, Zb, k3w, k3T, vw, kvw, padBase);
    padBase += 128;
    ns_uz2_kernel<<<dim3(2 * NB * 64 + 128), dim3(256), 0, stream>>>(
        Va, Zb, Ub, Z2b, k3w, k3T, vw, kvw, padBase);
    padBase += 128;
    ns_v_kernel<<<dim3(NB * 64 + 128), dim3(256), 0, stream>>>(
        Ub, Z2b, Zb, Va, k3w, k3T, vw, kvw, padBase);
    padBase += 128;
  }

  cvt_vinv_kernel<<<dim3(NM / 32, NM / 32, NB), dim3(256), 0, stream>>>(Va, Vinvt);
  gemm_a_mfma<<<dim3(NM / 128, NN / 128, NB), dim3(256), 0, stream>>>(k1bf, Vinvt, Abf);
  gemm_attn_mfma<<<dim3(NN / 128, NN / 128, NB), dim3(256), 0, stream>>>(Abf, k3T, attn);
  out_kernel<<<dim3(NB * NN / 32), dim3(256), 0, stream>>>(Abf, kvw, x, gamma, outp);
}